// Round 3
// baseline (940.252 us; speedup 1.0000x reference)
//
#include <hip/hip_runtime.h>
#include <cstddef>

#define Nn 32
#define Cc 128
#define Tt 128
#define Vv 25
#define BN_INV 0.9999950000374997f

// ---------------- workspace layout (float offsets), max 53,192,000 ----------
// WB (bf16 weights)    @ 0          (159,744 f as sh)
// QKBF  [n][192][3200] @ 200,000    (9,830,400)   dead after att_s
// S1BF  [n][128][3200] @ 200,000    (reuse, qk dead)
// ATSB  [n][3][t][625] @ 10,030,400 (3,840,000)
// Y2BF  [n][384][3200] @ 13,870,400 (19,660,800)
// SOUT  fp32           @ 33,531,200 (13,107,200)  live til TCN
// ATTB  [n][u][512]    @ 200,000    (reuse, s1 dead)
// XBARB                @ 1,300,000
// QKT   fp32           @ 1,600,000  (1,048,576)
// TMPB  [n][512][3200] @ 2,700,000  (26,214,400)  dead after t1 GEMM
// T1BF  [n][128][3200] @ 46,638,400 (6,553,600)
// TOUT  fp32           @ 2,700,000  (13,107,200, tmp dead)
// TOUTB                @ 15810000*? (6,553,600)
// NOTE (R3): ws memset REMOVED — every region is fully written before read
// within each launch (traced R3); output is a pure function of inputs.
// If post-timing divergence reappears, restore hipMemsetAsync here.

typedef __attribute__((ext_vector_type(8))) short bf16x8;
typedef __attribute__((ext_vector_type(4))) float f32x4;

__device__ __forceinline__ unsigned short f2bf(float f) {
    union { float f; unsigned u; } x; x.f = f;
    return (unsigned short)((x.u + 0x7FFFu + ((x.u >> 16) & 1u)) >> 16);
}
__device__ __forceinline__ float bf2f(unsigned short s) {
    union { unsigned u; float f; } x; x.u = ((unsigned)s) << 16;
    return x.f;
}

// =====================================================================
// MFMA bf16 GEMM, tile 128x128, 256 thr = 4 waves, K-block 32.
// R3: double-buffered LDS + unroll-2 two-register-set pipeline:
//   phase p: issue loads for block p+2 | stage regs(p+1)->LDS[(p+1)&1]
//            | frag-read LDS[p&1] + 16 MFMA | ONE barrier.
// Loads get ~1 full phase of latency cover; vmcnt is counted (newer loads
// stay in flight). Requires K % 64 == 0 (all call sites: 128/384/512/896).
// A: bf16 row-major [M][lda] @ A + n*an_stride
// BMODE 0: bf16 row-major [K][ldb]
// BMODE 4: fp32 row-major [K][ldb] (convert in loader)
// BMODE 1: TCN shifted: k=(kidx,c): B[k][col] = Bn[c*3200 + col + (kidx-3)*25]
// BMODE 3: tein: k=(h,t), col=(o,v): B[k][col] = Bn[h*409600 + o*3200 + t*25 + v]
// DMODE 0: addr = m*ldd + col ; DMODE 2: m=u, col=(c,v): addr = c*3200+u*25+v
// OM: 0 fp32 D only, 1 bf16 Dbf only, 2 both
// epilogue: val = acc (+bias); if(gg): val = val*g*BN_INV + bb + resp; lrelu
// =====================================================================

// fetch k-block K0 into (A0r, A1r, BQr[16]); A regs keep old (zero) if mg>=M
#define GFETCH(K0, A0r, A1r, BQr)                                              \
    {                                                                          \
        int mg = m0 + sm;                                                      \
        if (mg < M) {                                                          \
            const unsigned short* ap = An + (size_t)mg*lda + (K0) + skh*16;    \
            A0r = *(const bf16x8*)ap;                                          \
            A1r = *(const bf16x8*)(ap + 8);                                    \
        }                                                                      \
        if (BMODE == 0) {                                                      \
            const unsigned short* Bn = (const unsigned short*)Bv               \
                                     + (size_t)n*bn_stride;                    \
            _Pragma("unroll")                                                  \
            for (int j = 0; j < 16; ++j)                                       \
                BQr[j] = Bn[(size_t)((K0) + skq*16 + j)*ldb + bcol];           \
        } else if (BMODE == 4) {                                               \
            const float* Bf = (const float*)Bv + (size_t)n*bn_stride;          \
            _Pragma("unroll")                                                  \
            for (int j = 0; j < 16; ++j)                                       \
                BQr[j] = f2bf(Bf[(size_t)((K0) + skq*16 + j)*ldb + bcol]);     \
        } else if (BMODE == 1) {                                               \
            const unsigned short* Bn = (const unsigned short*)Bv               \
                                     + (size_t)n*bn_stride;                    \
            int kb = (K0) + skq*16;                                            \
            int kidx = kb >> 7, c0 = kb & 127;                                 \
            int e = bcol + (kidx - 3)*25;                                      \
            bool ok = ((unsigned)e < 3200u);                                   \
            _Pragma("unroll")                                                  \
            for (int j = 0; j < 16; ++j)                                       \
                BQr[j] = ok ? Bn[(size_t)(c0 + j)*3200 + e] : (unsigned short)0;\
        } else { /* BMODE 3 */                                                 \
            const unsigned short* Bn = (const unsigned short*)Bv               \
                                     + (size_t)n*bn_stride;                    \
            int kb = (K0) + skq*16;                                            \
            int h = kb >> 7, t0b = kb & 127;                                   \
            const unsigned short* bp = Bn + (size_t)h*409600 + (size_t)bo*3200 \
                                          + (size_t)t0b*25 + bv_;              \
            _Pragma("unroll")                                                  \
            for (int j = 0; j < 16; ++j) BQr[j] = bp[j*25];                    \
        }                                                                      \
    }

#define STAGE(BUF, A0r, A1r, BQr)                                              \
    {                                                                          \
        short* Ap = Al[BUF] + ((size_t)((sm>>4)*64 + (sm&15) + 32*skh))*8;     \
        *(bf16x8*)Ap = A0r;                                                    \
        *(bf16x8*)(Ap + 128) = A1r;                                            \
        short* Bp = Bl[BUF] + ((size_t)((scol>>4)*64 + (scol&15) + 32*skq))*8; \
        bf16x8 p0, p1;                                                         \
        _Pragma("unroll")                                                      \
        for (int j = 0; j < 8; ++j) { p0[j] = (short)BQr[j];                   \
                                      p1[j] = (short)BQr[8+j]; }               \
        *(bf16x8*)Bp = p0;                                                     \
        *(bf16x8*)(Bp + 128) = p1;                                             \
    }

#define COMP(BUF)                                                              \
    {                                                                          \
        bf16x8 afr[2], bfr[8];                                                 \
        afr[0] = *(const bf16x8*)(Al[BUF] + ((size_t)((2*wav+0)*64 + lane))*8);\
        afr[1] = *(const bf16x8*)(Al[BUF] + ((size_t)((2*wav+1)*64 + lane))*8);\
        _Pragma("unroll")                                                      \
        for (int c = 0; c < 8; ++c)                                            \
            bfr[c] = *(const bf16x8*)(Bl[BUF] + ((size_t)(c*64 + lane))*8);    \
        _Pragma("unroll")                                                      \
        for (int i = 0; i < 2; ++i)                                            \
            _Pragma("unroll")                                                  \
            for (int c = 0; c < 8; ++c)                                        \
                acc[i][c] = __builtin_amdgcn_mfma_f32_16x16x32_bf16(           \
                    afr[i], bfr[c], acc[i][c], 0, 0, 0);                       \
    }

template<int BMODE, int DMODE, int OM>
__global__ __launch_bounds__(256, 2) void gemm_k(
    const unsigned short* __restrict__ A, const void* __restrict__ Bv,
    float* __restrict__ D, unsigned short* __restrict__ Dbf,
    const float* __restrict__ resp, const float* __restrict__ bias,
    const float* __restrict__ gg, const float* __restrict__ bb,
    int M, int K, int lda, int ldb, int ldd,
    long an_stride, long bn_stride, long dn_stride, int gn)
{
    __shared__ short Al[2][8*64*8];   // 2 x 8KB: 8 m-frags x 64 lanes x 8 bf16
    __shared__ short Bl[2][8*64*8];   // 2 x 8KB: 8 col-frags

    const int n  = blockIdx.y;
    const int mt = blockIdx.x / gn;
    const int nt = blockIdx.x - mt*gn;
    const int m0 = mt*128;
    const int j0 = nt*128;

    const unsigned short* An = A + (size_t)n*an_stride;

    const int tid = threadIdx.x;
    const int wav = tid >> 6, lane = tid & 63;
    const int lq = lane >> 4, l16 = lane & 15;

    const int sm  = tid >> 1, skh = tid & 1;      // A staging: row, k-half
    const int scol = tid & 127, skq = tid >> 7;   // B staging: col, k-half
    const int bcol = j0 + scol;

    int bo = 0, bv_ = 0;
    if (BMODE == 3) { bo = bcol/25; bv_ = bcol - 25*bo; }

    f32x4 acc[2][8];
    #pragma unroll
    for (int i = 0; i < 2; ++i)
        #pragma unroll
        for (int c = 0; c < 8; ++c) acc[i][c] = (f32x4){0.f,0.f,0.f,0.f};

    bf16x8 a0A = (bf16x8){0,0,0,0,0,0,0,0}, a1A = a0A;
    bf16x8 a0B = a0A, a1B = a0A;
    unsigned short bqA[16], bqB[16];

    GFETCH(0,  a0A, a1A, bqA);
    GFETCH(32, a0B, a1B, bqB);
    STAGE(0, a0A, a1A, bqA);
    __syncthreads();

    for (int k0 = 0; k0 < K; k0 += 64) {
        // even phase: compute block k0 (LDS0); stage k0+32 (regs B -> LDS1);
        // issue loads for k0+64 (-> regs A, freed last odd phase)
        if (k0 + 64 < K) GFETCH(k0 + 64, a0A, a1A, bqA);
        STAGE(1, a0B, a1B, bqB);
        COMP(0);
        __syncthreads();

        // odd phase: compute block k0+32 (LDS1); stage k0+64 (A -> LDS0);
        // issue loads for k0+96 (-> regs B)
        if (k0 + 96 < K) GFETCH(k0 + 96, a0B, a1B, bqB);
        if (k0 + 64 < K) STAGE(0, a0A, a1A, bqA);
        COMP(1);
        __syncthreads();
    }

    // ---- epilogue: row = m0+(2w+i)*16+lq*4+r ; col = j0+ct*16+l16 ----
    #pragma unroll
    for (int i = 0; i < 2; ++i) {
        const int mbase = m0 + (2*wav + i)*16 + lq*4;
        #pragma unroll
        for (int ct = 0; ct < 8; ++ct) {
            const int col = j0 + ct*16 + l16;
            if (DMODE == 0) {
                #pragma unroll
                for (int r = 0; r < 4; ++r) {
                    const int mg = mbase + r;
                    if (mg < M) {
                        const size_t addr = (size_t)mg*ldd + col + (size_t)n*dn_stride;
                        float val = acc[i][ct][r] + (bias ? bias[mg] : 0.f);
                        if (gg) {
                            val = val*(gg[mg]*BN_INV) + bb[mg] + resp[addr];
                            val = val > 0.f ? val : 0.1f*val;
                        }
                        if (OM != 1) D[addr] = val;
                        if (OM >= 1) Dbf[addr] = f2bf(val);
                    }
                }
            } else { // DMODE 2
                const int c = col/25, v = col - 25*c;
                const float bi = bias ? bias[c] : 0.f;
                float gv = 0.f, b2 = 0.f;
                if (gg) { gv = gg[c]*BN_INV; b2 = bb[c]; }
                #pragma unroll
                for (int r = 0; r < 4; ++r) {
                    const int u = mbase + r;
                    const size_t addr = (size_t)c*3200 + (size_t)u*25 + v
                                      + (size_t)n*dn_stride;
                    float val = acc[i][ct][r] + bi;
                    if (gg) {
                        val = val*gv + b2 + resp[addr];
                        val = val > 0.f ? val : 0.1f*val;
                    }
                    if (OM != 1) D[addr] = val;
                    if (OM >= 1) Dbf[addr] = f2bf(val);
                }
            }
        }
    }
}

// weight prep: convert (and permute) all weights to bf16 in WB
__global__ void k_prep(const float* __restrict__ wis, const float* __restrict__ wos,
                       const float* __restrict__ wfs, const float* __restrict__ wit,
                       const float* __restrict__ wot, const float* __restrict__ wft,
                       const float* __restrict__ wtc, unsigned short* __restrict__ W) {
    int i = blockIdx.x*256 + threadIdx.x;
    if (i < 24576) { W[i] = f2bf(wis[i]); return; }          i -= 24576;
    if (i < 49152) { W[24576 + i] = f2bf(wos[i]); return; }  i -= 49152;
    if (i < 16384) { W[73728 + i] = f2bf(wfs[i]); return; }  i -= 16384;
    if (i < 32768) { W[90112 + i] = f2bf(wit[i]); return; }  i -= 32768;
    if (i < 65536) { // [(h*128+o)][c] <- wot[o][h*128+c]
        int ho = i >> 7, c = i & 127; int h = ho >> 7, o = ho & 127;
        W[122880 + i] = f2bf(wot[o*512 + h*128 + c]); return; } i -= 65536;
    if (i < 16384) { W[188416 + i] = f2bf(wft[i]); return; } i -= 16384;
    if (i < 114688) { // [o][kidx*128+c] <- wtc[(o*128+c)*7 + kidx]
        int o = i / 896; int r = i - o*896; int kidx = r >> 7, c = r & 127;
        W[204800 + i] = f2bf(wtc[(o*128 + c)*7 + kidx]); }
}

// spatial attention: atts_bf = att0 + tanh(q.k/32)*alpha  (reads bf16 qk)
__global__ void k_att_s(const unsigned short* __restrict__ qk,
                        const float* __restrict__ att0,
                        const float* __restrict__ alphas,
                        unsigned short* __restrict__ att) {
    int b = blockIdx.x;
    int n = b / (3*Tt); int rem = b - n*(3*Tt); int s = rem / Tt; int t = rem - s*Tt;
    __shared__ float qs[32*Vv], ks[32*Vv];
    const unsigned short* qp = qk + (size_t)n*614400 + (size_t)(s*32)*3200 + t*25;
    const unsigned short* kp = qk + (size_t)n*614400 + (size_t)(96 + s*32)*3200 + t*25;
    for (int i = threadIdx.x; i < 32*Vv; i += 256) {
        int c = i / Vv, v = i - c*Vv;
        qs[i] = bf2f(qp[(size_t)c*3200 + v]);
        ks[i] = bf2f(kp[(size_t)c*3200 + v]);
    }
    __syncthreads();
    float alpha = alphas[s];
    for (int i = threadIdx.x; i < Vv*Vv; i += 256) {
        int u = i / Vv, v = i - u*Vv;
        float a = 0.f;
        #pragma unroll
        for (int c = 0; c < 32; ++c) a += qs[c*Vv + u] * ks[c*Vv + v];
        att[(size_t)n*240000 + (size_t)s*80000 + (size_t)t*625 + i] =
            f2bf(att0[s*625 + i] + tanhf(a * (1.f/32.f)) * alpha);
    }
}

// =====================================================================
// MFMA spatial einsum: y2[(s*128+c)][(t0+tl)*25+v] = sum_u x[c][(t0+tl)*25+u]
//                      * att[s][t0+tl][u][v]
// One block per (n, 4 consecutive t). Block-diagonal B over the 4 t's:
// K = 4*32 (u padded 25->32), N = 4*25=100 (padded to 112 = 7 n-tiles).
// A staged bf16 in LDS with ((c&7)<<4) XOR swizzle. att scattered straight
// into MFMA B-fragment layout; Bf zeroed ONCE (scatter slot set is identical
// for all s, pads/cross-t slots stay zero => block-diagonal for free).
// Output cols tl*25+v are contiguous => 200B write runs per (s,c) row.
// =====================================================================
__global__ __launch_bounds__(256, 2) void k_eins_mfma(
    const float* __restrict__ X, const unsigned short* __restrict__ att,
    unsigned short* __restrict__ y2)
{
    __shared__ short Xf[128*128];     // [c][tl*32+u] bf16, swizzled (32KB)
    __shared__ short Bf[7*4*64*8];    // frag [nt][ks][lane][j] (28KB)

    const int n  = blockIdx.x >> 5;
    const int t0 = (blockIdx.x & 31) * 4;
    const int tid = threadIdx.x;
    const int wav = tid >> 6, lane = tid & 63;
    const int lq = lane >> 4, l16 = lane & 15;

    // zero B fragments once
    for (int i = tid; i < 7*4*64; i += 256)
        *(bf16x8*)(Bf + (size_t)i*8) = (bf16x8){0,0,0,0,0,0,0,0};

    // stage X -> Xf (pairs of u, coalesced 100B global runs, swizzled LDS)
    const float* xp = X + (size_t)n*409600;
    for (int i = tid; i < 8192; i += 256) {
        int u2 = (i & 15)*2, tl = (i >> 4) & 3, c = i >> 6;
        float f0 = 0.f, f1 = 0.f;
        if (u2 < 25) {
            const float* p = xp + (size_t)c*3200 + (t0 + tl)*25 + u2;
            f0 = p[0];
            if (u2 < 24) f1 = p[1];
        }
        unsigned pk = (unsigned)f2bf(f0) | ((unsigned)f2bf(f1) << 16);
        int byte = (i*4) ^ ((c & 7) << 4);
        *(unsigned*)((char*)Xf + byte) = pk;
    }
    __syncthreads();

    // hoisted A fragments: afr[i][ks] for m-tiles {2w, 2w+1} (shared by all s)
    bf16x8 afr[2][4];
    #pragma unroll
    for (int i = 0; i < 2; ++i) {
        const int c = (2*wav + i)*16 + l16;
        #pragma unroll
        for (int ks = 0; ks < 4; ++ks) {
            int byte = ((c*128 + ks*32 + lq*8)*2) ^ ((c & 7) << 4);
            afr[i][ks] = *(const bf16x8*)((const char*)Xf + byte);
        }
    }

    for (int s = 0; s < 3; ++s) {
        // scatter att[n,s,t0+tl,u,v] -> B frag slot (k=tl*32+u, col=tl*25+v)
        const unsigned short* ap = att + (size_t)n*240000 + (size_t)s*80000
                                       + (size_t)t0*625;
        for (int j = tid; j < 2500; j += 256) {
            int tl = j / 625, r = j - tl*625;
            int u = r / 25, v = r - u*25;
            int col = tl*25 + v;
            int l = ((u >> 3) << 4) | (col & 15);
            int nt = col >> 4;
            Bf[(size_t)((nt*4 + tl)*64 + l)*8 + (u & 7)] = (short)ap[j];
        }
        __syncthreads();

        f32x4 acc[2][7];
        #pragma unroll
        for (int i = 0; i < 2; ++i)
            #pragma unroll
            for (int nt = 0; nt < 7; ++nt) acc[i][nt] = (f32x4){0.f,0.f,0.f,0.f};

        #pragma unroll
        for (int ks = 0; ks < 4; ++ks) {
            bf16x8 bfr[7];
            #pragma unroll
            for (int nt = 0; nt < 7; ++nt)
                bfr[nt] = *(const bf16x8*)(Bf + (size_t)((nt*4 + ks)*64 + lane)*8);
            #pragma unroll
            for (int i = 0; i < 2; ++i)
                #pragma unroll
                for (int nt = 0; nt < 7; ++nt)
                    acc[i][nt] = __builtin_amdgcn_mfma_f32_16x16x32_bf16(
                        afr[i][ks], bfr[nt], acc[i][nt], 0, 0, 0);
        }

        // row=(2w+i)*16+lq*4+r, col=nt*16+l16 (<100): contiguous along col
        unsigned short* yb = y2 + (size_t)n*1228800 + (size_t)(s*128)*3200 + t0*25;
        #pragma unroll
        for (int i = 0; i < 2; ++i) {
            const int row = (2*wav + i)*16 + lq*4;
            #pragma unroll
            for (int nt = 0; nt < 7; ++nt) {
                const int col = nt*16 + l16;
                if (col < 100) {
                    unsigned short* yp = yb + (size_t)row*3200 + col;
                    #pragma unroll
                    for (int r = 0; r < 4; ++r)
                        yp[(size_t)r*3200] = f2bf(acc[i][nt][r]);
                }
            }
        }
        __syncthreads();
    }
}

// xbar_bf[n*16384 + c*128 + t] = mean_v sout
__global__ void k_mean(const float* __restrict__ X, unsigned short* __restrict__ xb) {
    int idx = blockIdx.x*256 + threadIdx.x;
    if (idx >= Nn*Cc*Tt) return;
    const float* p = X + (size_t)idx*25;
    float s = 0.f;
    #pragma unroll
    for (int v = 0; v < Vv; ++v) s += p[v];
    xb[idx] = f2bf(s * (1.f/25.f));
}

// temporal attention: attb_bf[n][u][(h*128+t)] = mask*alpha*tanh(dot/32)
__global__ void k_att_t(const float* __restrict__ qkt, const float* __restrict__ af,
                        const float* __restrict__ ab, unsigned short* __restrict__ attb) {
    int n = blockIdx.x >> 2, h = blockIdx.x & 3;
    __shared__ float qs[32*Tt], ks[32*Tt];
    const float* qp = qkt + (size_t)n*32768 + (size_t)(h*32)*128;
    const float* kp = qkt + (size_t)n*32768 + (size_t)(128 + h*32)*128;
    for (int i = threadIdx.x; i < 32*Tt; i += 256) { qs[i] = qp[i]; ks[i] = kp[i]; }
    __syncthreads();
    float alpha = (h < 2) ? af[h] : ab[h-2];
    for (int i = threadIdx.x; i < Tt*Tt; i += 256) {
        int u = i >> 7, t = i & 127;
        bool keep = (h < 2) ? (t >= u) : (t <= u);
        float val = 0.f;
        if (keep) {
            float a = 0.f;
            #pragma unroll
            for (int c = 0; c < 32; ++c) a += qs[c*Tt + t] * ks[c*Tt + u];
            val = tanhf(a * (1.f/32.f)) * alpha;
        }
        attb[(size_t)n*65536 + (size_t)u*512 + h*128 + t] = f2bf(val);
    }
}

extern "C" void kernel_launch(void* const* d_in, const int* in_sizes, int n_in,
                              void* d_out, int out_size, void* d_ws, size_t ws_size,
                              hipStream_t stream) {
    const float* x       = (const float*)d_in[0];
    const float* w_in_s  = (const float*)d_in[1];
    const float* b_in_s  = (const float*)d_in[2];
    const float* att0s   = (const float*)d_in[3];
    const float* alphas  = (const float*)d_in[4];
    const float* w_out_s = (const float*)d_in[5];
    const float* b_out_s = (const float*)d_in[6];
    const float* g_out_s = (const float*)d_in[7];
    const float* be_out_s= (const float*)d_in[8];
    const float* w_ff_s  = (const float*)d_in[9];
    const float* b_ff_s  = (const float*)d_in[10];
    const float* g_ff_s  = (const float*)d_in[11];
    const float* be_ff_s = (const float*)d_in[12];
    const float* w_in_t  = (const float*)d_in[13];
    const float* b_in_t  = (const float*)d_in[14];
    const float* alphat_f= (const float*)d_in[15];
    const float* alphat_b= (const float*)d_in[16];
    const float* w_out_t = (const float*)d_in[17];
    const float* b_out_t = (const float*)d_in[18];
    const float* g_out_t = (const float*)d_in[19];
    const float* be_out_t= (const float*)d_in[20];
    const float* w_ff_t  = (const float*)d_in[21];
    const float* b_ff_t  = (const float*)d_in[22];
    const float* g_ff_t  = (const float*)d_in[23];
    const float* be_ff_t = (const float*)d_in[24];
    const float* w_tcn   = (const float*)d_in[25];
    const float* b_tcn   = (const float*)d_in[26];
    const float* g_tcn   = (const float*)d_in[27];
    const float* be_tcn  = (const float*)d_in[28];

    float* ws = (float*)d_ws;
    unsigned short* WB    = (unsigned short*)ws;
    unsigned short* QKBF  = (unsigned short*)(ws + 200000);
    unsigned short* S1BF  = (unsigned short*)(ws + 200000);
    unsigned short* ATSB  = (unsigned short*)(ws + 10030400);
    unsigned short* Y2BF  = (unsigned short*)(ws + 13870400);
    float*          SOUT  = ws + 33531200;
    unsigned short* ATTB  = (unsigned short*)(ws + 200000);
    unsigned short* XBARB = (unsigned short*)(ws + 1300000);
    float*          QKT   = ws + 1600000;
    unsigned short* TMPB  = (unsigned short*)(ws + 2700000);
    unsigned short* T1BF  = (unsigned short*)(ws + 46638400);
    float*          TOUT  = ws + 2700000;
    unsigned short* TOUTB = (unsigned short*)(ws + 15810000);
    float* out = (float*)d_out;

    unsigned short* wbis = WB;
    unsigned short* wbos = WB + 24576;
    unsigned short* wbfs = WB + 73728;
    unsigned short* wbit = WB + 90112;
    unsigned short* wbot = WB + 122880;
    unsigned short* wbft = WB + 188416;
    unsigned short* wbtc = WB + 204800;

    dim3 blk(256);
    const float* NUL = nullptr;

    k_prep<<<1248, blk, 0, stream>>>(w_in_s, w_out_s, w_ff_s, w_in_t,
                                     w_out_t, w_ff_t, w_tcn, WB);

    // ---- spatial ----
    // qk_bf = W_in_s @ x + b      (M=192, K=128, B fp32)
    gemm_k<4,0,1><<<dim3(50,32), blk, 0, stream>>>(
        wbis, x, nullptr, QKBF, NUL, b_in_s, NUL, NUL,
        192, 128, 128, 3200, 3200, 0L, 409600L, 614400L, 25);
    k_att_s<<<Nn*3*Tt, blk, 0, stream>>>(QKBF, att0s, alphas, ATSB);
    k_eins_mfma<<<dim3(Nn*32), blk, 0, stream>>>(x, ATSB, Y2BF);
    // s1_bf = lrelu(x + bn(W_out_s @ y2 + b))   (K=384 fused over heads)
    gemm_k<0,0,1><<<dim3(25,32), blk, 0, stream>>>(
        wbos, Y2BF, nullptr, S1BF, x, b_out_s, g_out_s, be_out_s,
        128, 384, 384, 3200, 3200, 0L, 1228800L, 409600L, 25);
    // sout = lrelu(x + bn(W_ff_s @ s1 + b))
    gemm_k<0,0,0><<<dim3(25,32), blk, 0, stream>>>(
        wbfs, S1BF, SOUT, nullptr, x, b_ff_s, g_ff_s, be_ff_s,
        128, 128, 128, 3200, 3200, 0L, 409600L, 409600L, 25);

    // ---- temporal ----
    k_mean<<<2048, blk, 0, stream>>>(SOUT, XBARB);
    // qkt = W_in_t @ xbar + b     (M=256, K=128, N=128)
    gemm_k<0,0,0><<<dim3(2,32), blk, 0, stream>>>(
        wbit, XBARB, QKT, nullptr, NUL, b_in_t, NUL, NUL,
        256, 128, 128, 128, 128, 0L, 16384L, 32768L, 1);
    k_att_t<<<Nn*4, blk, 0, stream>>>(QKT, alphat_f, alphat_b, ATTB);
    // tmp_bf[(h,o)] = W_out_t_perm @ sout   (M=512, B fp32)
    gemm_k<4,0,1><<<dim3(100,32), blk, 0, stream>>>(
        wbot, SOUT, nullptr, TMPB, NUL, NUL, NUL, NUL,
        512, 128, 128, 3200, 3200, 0L, 409600L, 1638400L, 25);
    // t1_bf = lrelu(sout + bn(att @ tmp + b))  (K=512 fused over heads, DMODE2)
    gemm_k<3,2,1><<<dim3(25,32), blk, 0, stream>>>(
        ATTB, TMPB, nullptr, T1BF, SOUT, b_out_t, g_out_t, be_out_t,
        128, 512, 512, 3200, 3200, 65536L, 1638400L, 409600L, 25);
    // tout(+bf) = lrelu(sout + bn(W_ff_t @ t1 + b))
    gemm_k<0,0,2><<<dim3(25,32), blk, 0, stream>>>(
        wbft, T1BF, TOUT, TOUTB, SOUT, b_ff_t, g_ff_t, be_ff_t,
        128, 128, 128, 3200, 3200, 0L, 409600L, 409600L, 25);

    // ---- TCN ----
    // out = lrelu(tout + bn(conv7(tout) + b))   (K=896, shifted bf16 B)
    gemm_k<1,0,0><<<dim3(25,32), blk, 0, stream>>>(
        wbtc, TOUTB, out, nullptr, TOUT, b_tcn, g_tcn, be_tcn,
        128, 896, 896, 3200, 3200, 0L, 409600L, 409600L, 25);
}

// Round 4
// 710.042 us; speedup vs baseline: 1.3242x; 1.3242x over previous
//
#include <hip/hip_runtime.h>
#include <cstddef>

#define Nn 32
#define Cc 128
#define Tt 128
#define Vv 25
#define BN_INV 0.9999950000374997f

// ---------------- workspace layout (float offsets), max 53,192,000 ----------
// WB (bf16 weights)    @ 0          (159,744 f as sh)
// QKBF  [n][192][3200] @ 200,000    (9,830,400)   dead after att_s
// S1BF  [n][128][3200] @ 200,000    (reuse, qk dead)
// ATSB  [n][3][t][625] @ 10,030,400 (3,840,000)
// Y2BF  [n][384][3200] @ 13,870,400 (19,660,800)
// SOUT  fp32           @ 33,531,200 (13,107,200)  live til TCN
// ATTB  [n][u][512]    @ 200,000    (reuse, s1 dead)
// XBARB                @ 1,300,000
// QKT   fp32           @ 1,600,000  (1,048,576)
// TMPB  [n][512][3200] @ 2,700,000  (26,214,400)  dead after t1 GEMM
// T1BF  [n][128][3200] @ 46,638,400 (6,553,600)
// TOUT  fp32           @ 2,700,000  (13,107,200, tmp dead)
// TOUTB @ 15,810,000   (6,553,600)
// NOTE: ws memset removed (R3): every region fully written before read within
// each launch; R3 verified pass without it. If divergence recurs, restore.
// R3 LESSON: explicit LDS double-buffer pipeline REGRESSED (105->145us TCN;
// occupancy 26->20%) — matches guide m99/m100. Keep single-buffer 2-barrier.
// R4: XCD-aware bijective block swizzle — all blocks of one n on one XCD so
// per-n B-slices (<1.6MB) stay L2-resident (TCN FETCH was 126MB vs 65 ideal).

typedef __attribute__((ext_vector_type(8))) short bf16x8;
typedef __attribute__((ext_vector_type(4))) float f32x4;

__device__ __forceinline__ unsigned short f2bf(float f) {
    union { float f; unsigned u; } x; x.f = f;
    return (unsigned short)((x.u + 0x7FFFu + ((x.u >> 16) & 1u)) >> 16);
}
__device__ __forceinline__ float bf2f(unsigned short s) {
    union { unsigned u; float f; } x; x.u = ((unsigned)s) << 16;
    return x.f;
}

// =====================================================================
// MFMA bf16 GEMM, tile 128x128, 256 thr = 4 waves, K-block 32 (R1 structure).
// 1D grid, nwg = gxn*32 (nwg % 8 == 0 at every call site). XCD swizzle:
//   w = (b&7)*(nwg>>3) + (b>>3); n = w/gxn; rem -> (mt, nt).
// Consecutive dispatch ids round-robin XCDs, so each XCD gets a contiguous
// w-range = whole n's; per-n B/resp slices stay in that XCD's L2.
// A: bf16 row-major [M][lda] @ A + n*an_stride
// BMODE 0: bf16 row-major [K][ldb]
// BMODE 4: fp32 row-major [K][ldb] (convert in loader)
// BMODE 1: TCN shifted: k=(kidx,c): B[k][col] = Bn[c*3200 + col + (kidx-3)*25]
// BMODE 3: tein: k=(h,t), col=(o,v): B[k][col] = Bn[h*409600 + o*3200 + t*25 + v]
// DMODE 0: addr = m*ldd + col ; DMODE 2: m=u, col=(c,v): addr = c*3200+u*25+v
// OM: 0 fp32 D only, 1 bf16 Dbf only, 2 both
// epilogue: val = acc (+bias); if(gg): val = val*g*BN_INV + bb + resp; lrelu
// =====================================================================
template<int BMODE, int DMODE, int OM>
__global__ __launch_bounds__(256, 2) void gemm_k(
    const unsigned short* __restrict__ A, const void* __restrict__ Bv,
    float* __restrict__ D, unsigned short* __restrict__ Dbf,
    const float* __restrict__ resp, const float* __restrict__ bias,
    const float* __restrict__ gg, const float* __restrict__ bb,
    int M, int K, int lda, int ldb, int ldd,
    long an_stride, long bn_stride, long dn_stride, int gn, int gxn)
{
    __shared__ short Al[8*64*8];   // 8 m-frags x 64 lane-slots x 8 bf16
    __shared__ short Bl[8*64*8];   // 8 col-frags x 64 lane-slots x 8 bf16

    // ---- XCD-aware bijective swizzle (nwg % 8 == 0 guaranteed) ----
    const int nwg = gridDim.x;
    const int b   = blockIdx.x;
    const int w   = (b & 7)*(nwg >> 3) + (b >> 3);
    const int n   = w / gxn;
    const int rem = w - n*gxn;
    const int mt  = rem / gn;
    const int nt  = rem - mt*gn;
    const int m0 = mt*128;
    const int j0 = nt*128;

    const unsigned short* An = A + (size_t)n*an_stride;

    const int tid = threadIdx.x;
    const int wav = tid >> 6, lane = tid & 63;
    const int lq = lane >> 4, l16 = lane & 15;

    const int sm  = tid >> 1, skh = tid & 1;      // A staging: row, k-half
    const int scol = tid & 127, skq = tid >> 7;   // B staging: col, k-half
    const int bcol = j0 + scol;

    int bo = 0, bv_ = 0;
    if (BMODE == 3) { bo = bcol/25; bv_ = bcol - 25*bo; }

    f32x4 acc[2][8];
    #pragma unroll
    for (int i = 0; i < 2; ++i)
        #pragma unroll
        for (int c = 0; c < 8; ++c) acc[i][c] = (f32x4){0.f,0.f,0.f,0.f};

    for (int k0 = 0; k0 < K; k0 += 32) {
        // ---- A fetch: 16 bf16, row m0+sm, k = k0+skh*16 .. +15 ----
        bf16x8 a0 = (bf16x8){0,0,0,0,0,0,0,0}, a1 = a0;
        {
            int mg = m0 + sm;
            if (mg < M) {
                const unsigned short* ap = An + (size_t)mg*lda + k0 + skh*16;
                a0 = *(const bf16x8*)ap;
                a1 = *(const bf16x8*)(ap + 8);
            }
        }
        // ---- B fetch: 16 elems, col bcol, k = k0+skq*16+j ----
        unsigned short bq[16];
        if (BMODE == 0) {
            const unsigned short* Bn = (const unsigned short*)Bv + (size_t)n*bn_stride;
            #pragma unroll
            for (int j = 0; j < 16; ++j)
                bq[j] = Bn[(size_t)(k0 + skq*16 + j)*ldb + bcol];
        } else if (BMODE == 4) {
            const float* Bf = (const float*)Bv + (size_t)n*bn_stride;
            #pragma unroll
            for (int j = 0; j < 16; ++j)
                bq[j] = f2bf(Bf[(size_t)(k0 + skq*16 + j)*ldb + bcol]);
        } else if (BMODE == 1) {
            const unsigned short* Bn = (const unsigned short*)Bv + (size_t)n*bn_stride;
            int kb = k0 + skq*16;
            int kidx = kb >> 7, c0 = kb & 127;
            int e = bcol + (kidx - 3)*25;
            bool ok = ((unsigned)e < 3200u);
            #pragma unroll
            for (int j = 0; j < 16; ++j)
                bq[j] = ok ? Bn[(size_t)(c0 + j)*3200 + e] : (unsigned short)0;
        } else { // BMODE 3
            const unsigned short* Bn = (const unsigned short*)Bv + (size_t)n*bn_stride;
            int kb = k0 + skq*16;
            int h = kb >> 7, t0 = kb & 127;
            const unsigned short* bp = Bn + (size_t)h*409600 + (size_t)bo*3200
                                          + (size_t)t0*25 + bv_;
            #pragma unroll
            for (int j = 0; j < 16; ++j) bq[j] = bp[j*25];
        }

        __syncthreads();   // previous tile consumed
        {
            short* Ap = Al + ((size_t)((sm>>4)*64 + (sm&15) + 32*skh))*8;
            *(bf16x8*)Ap = a0;
            *(bf16x8*)(Ap + 128) = a1;       // +16 lane-slots
        }
        {
            short* Bp = Bl + ((size_t)((scol>>4)*64 + (scol&15) + 32*skq))*8;
            bf16x8 p0, p1;
            #pragma unroll
            for (int j = 0; j < 8; ++j) { p0[j] = (short)bq[j]; p1[j] = (short)bq[8+j]; }
            *(bf16x8*)Bp = p0;
            *(bf16x8*)(Bp + 128) = p1;
        }
        __syncthreads();

        bf16x8 afr[2], bfr[8];
        afr[0] = *(const bf16x8*)(Al + ((size_t)((2*wav+0)*64 + lane))*8);
        afr[1] = *(const bf16x8*)(Al + ((size_t)((2*wav+1)*64 + lane))*8);
        #pragma unroll
        for (int c = 0; c < 8; ++c)
            bfr[c] = *(const bf16x8*)(Bl + ((size_t)(c*64 + lane))*8);
        #pragma unroll
        for (int i = 0; i < 2; ++i)
            #pragma unroll
            for (int c = 0; c < 8; ++c)
                acc[i][c] = __builtin_amdgcn_mfma_f32_16x16x32_bf16(
                    afr[i], bfr[c], acc[i][c], 0, 0, 0);
    }

    // ---- epilogue: row = m0+(2w+i)*16+lq*4+r ; col = j0+ct*16+l16 ----
    #pragma unroll
    for (int i = 0; i < 2; ++i) {
        const int mbase = m0 + (2*wav + i)*16 + lq*4;
        #pragma unroll
        for (int ct = 0; ct < 8; ++ct) {
            const int col = j0 + ct*16 + l16;
            if (DMODE == 0) {
                #pragma unroll
                for (int r = 0; r < 4; ++r) {
                    const int mg = mbase + r;
                    if (mg < M) {
                        const size_t addr = (size_t)mg*ldd + col + (size_t)n*dn_stride;
                        float val = acc[i][ct][r] + (bias ? bias[mg] : 0.f);
                        if (gg) {
                            val = val*(gg[mg]*BN_INV) + bb[mg] + resp[addr];
                            val = val > 0.f ? val : 0.1f*val;
                        }
                        if (OM != 1) D[addr] = val;
                        if (OM >= 1) Dbf[addr] = f2bf(val);
                    }
                }
            } else { // DMODE 2
                const int c = col/25, v = col - 25*c;
                const float bi = bias ? bias[c] : 0.f;
                float gv = 0.f, b2 = 0.f;
                if (gg) { gv = gg[c]*BN_INV; b2 = bb[c]; }
                #pragma unroll
                for (int r = 0; r < 4; ++r) {
                    const int u = mbase + r;
                    const size_t addr = (size_t)c*3200 + (size_t)u*25 + v
                                      + (size_t)n*dn_stride;
                    float val = acc[i][ct][r] + bi;
                    if (gg) {
                        val = val*gv + b2 + resp[addr];
                        val = val > 0.f ? val : 0.1f*val;
                    }
                    if (OM != 1) D[addr] = val;
                    if (OM >= 1) Dbf[addr] = f2bf(val);
                }
            }
        }
    }
}

// weight prep: convert (and permute) all weights to bf16 in WB
__global__ void k_prep(const float* __restrict__ wis, const float* __restrict__ wos,
                       const float* __restrict__ wfs, const float* __restrict__ wit,
                       const float* __restrict__ wot, const float* __restrict__ wft,
                       const float* __restrict__ wtc, unsigned short* __restrict__ W) {
    int i = blockIdx.x*256 + threadIdx.x;
    if (i < 24576) { W[i] = f2bf(wis[i]); return; }          i -= 24576;
    if (i < 49152) { W[24576 + i] = f2bf(wos[i]); return; }  i -= 49152;
    if (i < 16384) { W[73728 + i] = f2bf(wfs[i]); return; }  i -= 16384;
    if (i < 32768) { W[90112 + i] = f2bf(wit[i]); return; }  i -= 32768;
    if (i < 65536) { // [(h*128+o)][c] <- wot[o][h*128+c]
        int ho = i >> 7, c = i & 127; int h = ho >> 7, o = ho & 127;
        W[122880 + i] = f2bf(wot[o*512 + h*128 + c]); return; } i -= 65536;
    if (i < 16384) { W[188416 + i] = f2bf(wft[i]); return; } i -= 16384;
    if (i < 114688) { // [o][kidx*128+c] <- wtc[(o*128+c)*7 + kidx]
        int o = i / 896; int r = i - o*896; int kidx = r >> 7, c = r & 127;
        W[204800 + i] = f2bf(wtc[(o*128 + c)*7 + kidx]); }
}

// spatial attention: atts_bf = att0 + tanh(q.k/32)*alpha  (reads bf16 qk)
__global__ void k_att_s(const unsigned short* __restrict__ qk,
                        const float* __restrict__ att0,
                        const float* __restrict__ alphas,
                        unsigned short* __restrict__ att) {
    int b = blockIdx.x;
    int n = b / (3*Tt); int rem = b - n*(3*Tt); int s = rem / Tt; int t = rem - s*Tt;
    __shared__ float qs[32*Vv], ks[32*Vv];
    const unsigned short* qp = qk + (size_t)n*614400 + (size_t)(s*32)*3200 + t*25;
    const unsigned short* kp = qk + (size_t)n*614400 + (size_t)(96 + s*32)*3200 + t*25;
    for (int i = threadIdx.x; i < 32*Vv; i += 256) {
        int c = i / Vv, v = i - c*Vv;
        qs[i] = bf2f(qp[(size_t)c*3200 + v]);
        ks[i] = bf2f(kp[(size_t)c*3200 + v]);
    }
    __syncthreads();
    float alpha = alphas[s];
    for (int i = threadIdx.x; i < Vv*Vv; i += 256) {
        int u = i / Vv, v = i - u*Vv;
        float a = 0.f;
        #pragma unroll
        for (int c = 0; c < 32; ++c) a += qs[c*Vv + u] * ks[c*Vv + v];
        att[(size_t)n*240000 + (size_t)s*80000 + (size_t)t*625 + i] =
            f2bf(att0[s*625 + i] + tanhf(a * (1.f/32.f)) * alpha);
    }
}

// =====================================================================
// MFMA spatial einsum: y2[(s*128+c)][(t0+tl)*25+v] = sum_u x[c][(t0+tl)*25+u]
//                      * att[s][t0+tl][u][v]
// One block per (n, 4 consecutive t). Block-diagonal B over the 4 t's:
// K = 4*32 (u padded 25->32), N = 4*25=100 (padded to 112 = 7 n-tiles).
// A staged bf16 in LDS with ((c&7)<<4) XOR swizzle. att scattered straight
// into MFMA B-fragment layout; Bf zeroed ONCE (scatter slot set is identical
// for all s, pads/cross-t slots stay zero => block-diagonal for free).
// Output cols tl*25+v are contiguous => 200B write runs per (s,c) row.
// =====================================================================
__global__ __launch_bounds__(256, 2) void k_eins_mfma(
    const float* __restrict__ X, const unsigned short* __restrict__ att,
    unsigned short* __restrict__ y2)
{
    __shared__ short Xf[128*128];     // [c][tl*32+u] bf16, swizzled (32KB)
    __shared__ short Bf[7*4*64*8];    // frag [nt][ks][lane][j] (28KB)

    const int n  = blockIdx.x >> 5;
    const int t0 = (blockIdx.x & 31) * 4;
    const int tid = threadIdx.x;
    const int wav = tid >> 6, lane = tid & 63;
    const int lq = lane >> 4, l16 = lane & 15;

    // zero B fragments once
    for (int i = tid; i < 7*4*64; i += 256)
        *(bf16x8*)(Bf + (size_t)i*8) = (bf16x8){0,0,0,0,0,0,0,0};

    // stage X -> Xf (pairs of u, coalesced 100B global runs, swizzled LDS)
    const float* xp = X + (size_t)n*409600;
    for (int i = tid; i < 8192; i += 256) {
        int u2 = (i & 15)*2, tl = (i >> 4) & 3, c = i >> 6;
        float f0 = 0.f, f1 = 0.f;
        if (u2 < 25) {
            const float* p = xp + (size_t)c*3200 + (t0 + tl)*25 + u2;
            f0 = p[0];
            if (u2 < 24) f1 = p[1];
        }
        unsigned pk = (unsigned)f2bf(f0) | ((unsigned)f2bf(f1) << 16);
        int byte = (i*4) ^ ((c & 7) << 4);
        *(unsigned*)((char*)Xf + byte) = pk;
    }
    __syncthreads();

    // hoisted A fragments: afr[i][ks] for m-tiles {2w, 2w+1} (shared by all s)
    bf16x8 afr[2][4];
    #pragma unroll
    for (int i = 0; i < 2; ++i) {
        const int c = (2*wav + i)*16 + l16;
        #pragma unroll
        for (int ks = 0; ks < 4; ++ks) {
            int byte = ((c*128 + ks*32 + lq*8)*2) ^ ((c & 7) << 4);
            afr[i][ks] = *(const bf16x8*)((const char*)Xf + byte);
        }
    }

    for (int s = 0; s < 3; ++s) {
        // scatter att[n,s,t0+tl,u,v] -> B frag slot (k=tl*32+u, col=tl*25+v)
        const unsigned short* ap = att + (size_t)n*240000 + (size_t)s*80000
                                       + (size_t)t0*625;
        for (int j = tid; j < 2500; j += 256) {
            int tl = j / 625, r = j - tl*625;
            int u = r / 25, v = r - u*25;
            int col = tl*25 + v;
            int l = ((u >> 3) << 4) | (col & 15);
            int nt = col >> 4;
            Bf[(size_t)((nt*4 + tl)*64 + l)*8 + (u & 7)] = (short)ap[j];
        }
        __syncthreads();

        f32x4 acc[2][7];
        #pragma unroll
        for (int i = 0; i < 2; ++i)
            #pragma unroll
            for (int nt = 0; nt < 7; ++nt) acc[i][nt] = (f32x4){0.f,0.f,0.f,0.f};

        #pragma unroll
        for (int ks = 0; ks < 4; ++ks) {
            bf16x8 bfr[7];
            #pragma unroll
            for (int nt = 0; nt < 7; ++nt)
                bfr[nt] = *(const bf16x8*)(Bf + (size_t)((nt*4 + ks)*64 + lane)*8);
            #pragma unroll
            for (int i = 0; i < 2; ++i)
                #pragma unroll
                for (int nt = 0; nt < 7; ++nt)
                    acc[i][nt] = __builtin_amdgcn_mfma_f32_16x16x32_bf16(
                        afr[i][ks], bfr[nt], acc[i][nt], 0, 0, 0);
        }

        // row=(2w+i)*16+lq*4+r, col=nt*16+l16 (<100): contiguous along col
        unsigned short* yb = y2 + (size_t)n*1228800 + (size_t)(s*128)*3200 + t0*25;
        #pragma unroll
        for (int i = 0; i < 2; ++i) {
            const int row = (2*wav + i)*16 + lq*4;
            #pragma unroll
            for (int nt = 0; nt < 7; ++nt) {
                const int col = nt*16 + l16;
                if (col < 100) {
                    unsigned short* yp = yb + (size_t)row*3200 + col;
                    #pragma unroll
                    for (int r = 0; r < 4; ++r)
                        yp[(size_t)r*3200] = f2bf(acc[i][nt][r]);
                }
            }
        }
        __syncthreads();
    }
}

// xbar_bf[n*16384 + c*128 + t] = mean_v sout
__global__ void k_mean(const float* __restrict__ X, unsigned short* __restrict__ xb) {
    int idx = blockIdx.x*256 + threadIdx.x;
    if (idx >= Nn*Cc*Tt) return;
    const float* p = X + (size_t)idx*25;
    float s = 0.f;
    #pragma unroll
    for (int v = 0; v < Vv; ++v) s += p[v];
    xb[idx] = f2bf(s * (1.f/25.f));
}

// temporal attention: attb_bf[n][u][(h*128+t)] = mask*alpha*tanh(dot/32)
__global__ void k_att_t(const float* __restrict__ qkt, const float* __restrict__ af,
                        const float* __restrict__ ab, unsigned short* __restrict__ attb) {
    int n = blockIdx.x >> 2, h = blockIdx.x & 3;
    __shared__ float qs[32*Tt], ks[32*Tt];
    const float* qp = qkt + (size_t)n*32768 + (size_t)(h*32)*128;
    const float* kp = qkt + (size_t)n*32768 + (size_t)(128 + h*32)*128;
    for (int i = threadIdx.x; i < 32*Tt; i += 256) { qs[i] = qp[i]; ks[i] = kp[i]; }
    __syncthreads();
    float alpha = (h < 2) ? af[h] : ab[h-2];
    for (int i = threadIdx.x; i < Tt*Tt; i += 256) {
        int u = i >> 7, t = i & 127;
        bool keep = (h < 2) ? (t >= u) : (t <= u);
        float val = 0.f;
        if (keep) {
            float a = 0.f;
            #pragma unroll
            for (int c = 0; c < 32; ++c) a += qs[c*Tt + t] * ks[c*Tt + u];
            val = tanhf(a * (1.f/32.f)) * alpha;
        }
        attb[(size_t)n*65536 + (size_t)u*512 + h*128 + t] = f2bf(val);
    }
}

extern "C" void kernel_launch(void* const* d_in, const int* in_sizes, int n_in,
                              void* d_out, int out_size, void* d_ws, size_t ws_size,
                              hipStream_t stream) {
    const float* x       = (const float*)d_in[0];
    const float* w_in_s  = (const float*)d_in[1];
    const float* b_in_s  = (const float*)d_in[2];
    const float* att0s   = (const float*)d_in[3];
    const float* alphas  = (const float*)d_in[4];
    const float* w_out_s = (const float*)d_in[5];
    const float* b_out_s = (const float*)d_in[6];
    const float* g_out_s = (const float*)d_in[7];
    const float* be_out_s= (const float*)d_in[8];
    const float* w_ff_s  = (const float*)d_in[9];
    const float* b_ff_s  = (const float*)d_in[10];
    const float* g_ff_s  = (const float*)d_in[11];
    const float* be_ff_s = (const float*)d_in[12];
    const float* w_in_t  = (const float*)d_in[13];
    const float* b_in_t  = (const float*)d_in[14];
    const float* alphat_f= (const float*)d_in[15];
    const float* alphat_b= (const float*)d_in[16];
    const float* w_out_t = (const float*)d_in[17];
    const float* b_out_t = (const float*)d_in[18];
    const float* g_out_t = (const float*)d_in[19];
    const float* be_out_t= (const float*)d_in[20];
    const float* w_ff_t  = (const float*)d_in[21];
    const float* b_ff_t  = (const float*)d_in[22];
    const float* g_ff_t  = (const float*)d_in[23];
    const float* be_ff_t = (const float*)d_in[24];
    const float* w_tcn   = (const float*)d_in[25];
    const float* b_tcn   = (const float*)d_in[26];
    const float* g_tcn   = (const float*)d_in[27];
    const float* be_tcn  = (const float*)d_in[28];

    float* ws = (float*)d_ws;
    unsigned short* WB    = (unsigned short*)ws;
    unsigned short* QKBF  = (unsigned short*)(ws + 200000);
    unsigned short* S1BF  = (unsigned short*)(ws + 200000);
    unsigned short* ATSB  = (unsigned short*)(ws + 10030400);
    unsigned short* Y2BF  = (unsigned short*)(ws + 13870400);
    float*          SOUT  = ws + 33531200;
    unsigned short* ATTB  = (unsigned short*)(ws + 200000);
    unsigned short* XBARB = (unsigned short*)(ws + 1300000);
    float*          QKT   = ws + 1600000;
    unsigned short* TMPB  = (unsigned short*)(ws + 2700000);
    unsigned short* T1BF  = (unsigned short*)(ws + 46638400);
    float*          TOUT  = ws + 2700000;
    unsigned short* TOUTB = (unsigned short*)(ws + 15810000);
    float* out = (float*)d_out;

    unsigned short* wbis = WB;
    unsigned short* wbos = WB + 24576;
    unsigned short* wbfs = WB + 73728;
    unsigned short* wbit = WB + 90112;
    unsigned short* wbot = WB + 122880;
    unsigned short* wbft = WB + 188416;
    unsigned short* wbtc = WB + 204800;

    dim3 blk(256);
    const float* NUL = nullptr;

    k_prep<<<1248, blk, 0, stream>>>(w_in_s, w_out_s, w_ff_s, w_in_t,
                                     w_out_t, w_ff_t, w_tcn, WB);

    // ---- spatial ----
    // qk_bf = W_in_s @ x + b      (M=192, K=128, B fp32) : 1600 blocks
    gemm_k<4,0,1><<<1600, blk, 0, stream>>>(
        wbis, x, nullptr, QKBF, NUL, b_in_s, NUL, NUL,
        192, 128, 128, 3200, 3200, 0L, 409600L, 614400L, 25, 50);
    k_att_s<<<Nn*3*Tt, blk, 0, stream>>>(QKBF, att0s, alphas, ATSB);
    k_eins_mfma<<<dim3(Nn*32), blk, 0, stream>>>(x, ATSB, Y2BF);
    // s1_bf = lrelu(x + bn(W_out_s @ y2 + b))   (K=384 fused over heads)
    gemm_k<0,0,1><<<800, blk, 0, stream>>>(
        wbos, Y2BF, nullptr, S1BF, x, b_out_s, g_out_s, be_out_s,
        128, 384, 384, 3200, 3200, 0L, 1228800L, 409600L, 25, 25);
    // sout = lrelu(x + bn(W_ff_s @ s1 + b))
    gemm_k<0,0,0><<<800, blk, 0, stream>>>(
        wbfs, S1BF, SOUT, nullptr, x, b_ff_s, g_ff_s, be_ff_s,
        128, 128, 128, 3200, 3200, 0L, 409600L, 409600L, 25, 25);

    // ---- temporal ----
    k_mean<<<2048, blk, 0, stream>>>(SOUT, XBARB);
    // qkt = W_in_t @ xbar + b     (M=256, K=128, N=128) : 64 blocks
    gemm_k<0,0,0><<<64, blk, 0, stream>>>(
        wbit, XBARB, QKT, nullptr, NUL, b_in_t, NUL, NUL,
        256, 128, 128, 128, 128, 0L, 16384L, 32768L, 1, 2);
    k_att_t<<<Nn*4, blk, 0, stream>>>(QKT, alphat_f, alphat_b, ATTB);
    // tmp_bf[(h,o)] = W_out_t_perm @ sout   (M=512, B fp32) : 3200 blocks
    gemm_k<4,0,1><<<3200, blk, 0, stream>>>(
        wbot, SOUT, nullptr, TMPB, NUL, NUL, NUL, NUL,
        512, 128, 128, 3200, 3200, 0L, 409600L, 1638400L, 25, 100);
    // t1_bf = lrelu(sout + bn(att @ tmp + b))  (K=512 fused over heads, DMODE2)
    gemm_k<3,2,1><<<800, blk, 0, stream>>>(
        ATTB, TMPB, nullptr, T1BF, SOUT, b_out_t, g_out_t, be_out_t,
        128, 512, 512, 3200, 3200, 65536L, 1638400L, 409600L, 25, 25);
    // tout(+bf) = lrelu(sout + bn(W_ff_t @ t1 + b))
    gemm_k<0,0,2><<<800, blk, 0, stream>>>(
        wbft, T1BF, TOUT, TOUTB, SOUT, b_ff_t, g_ff_t, be_ff_t,
        128, 128, 128, 3200, 3200, 0L, 409600L, 409600L, 25, 25);

    // ---- TCN ----
    // out = lrelu(tout + bn(conv7(tout) + b))   (K=896, shifted bf16 B)
    gemm_k<1,0,0><<<800, blk, 0, stream>>>(
        wbtc, TOUTB, out, nullptr, TOUT, b_tcn, g_tcn, be_tcn,
        128, 896, 896, 3200, 3200, 0L, 409600L, 409600L, 25, 25);
}